// Round 2
// baseline (306.281 us; speedup 1.0000x reference)
//
#include <hip/hip_runtime.h>
#include <math.h>

#define D_MODEL 4096
#define N_EXP   64
#define BM      64
#define BK      32
#define NTHR    256
#define KSTEPS  (D_MODEL / BK)   // 128

// out layout: [0 .. 2*ntok)       = weights (fp32)
//             [2*ntok .. 4*ntok)  = expert indices (written as fp32 values)
__global__ __launch_bounds__(NTHR, 2)
void moe_router_kernel(const float* __restrict__ x,
                       const float* __restrict__ W,
                       float* __restrict__ out, int ntok)
{
    // K-major tiles so fragment reads are ds_read_b128
    __shared__ float xs[BK][BM + 4];
    __shared__ float ws[BK][N_EXP + 4];

    const int t  = threadIdx.x;
    const int tx = t & 15;   // expert group: experts tx*4 .. tx*4+3
    const int ty = t >> 4;   // token group:  tokens ty*4 .. ty*4+3 (0..15)
    const int tok0 = blockIdx.x * BM;

    // staging decomposition: 512 float4 per (x,W) tile, 256 threads -> 2 rows each
    const int r0 = t >> 3;   // 0..31
    const int c0 = t & 7;    // 0..7 (float4 column)

    const float* xg  = x + (size_t)(tok0 + r0) * D_MODEL + 4 * c0;
    const float* xg2 = xg + (size_t)32 * D_MODEL;
    const float* wg  = W + (size_t)r0 * D_MODEL + 4 * c0;
    const float* wg2 = wg + (size_t)32 * D_MODEL;

    // fp32 chunk accumulators (reset every 2 K-tiles = 64 terms) + fp64 master.
    // Sequential fp32 over 4096 terms has error ~5e-6 which flips near-tie
    // top-k ordering vs the numpy reference; chunked fp32 -> fp64 fold gives
    // ~7e-7, same accuracy class as the reference.
    float  acc[4][4];
    double dacc[4][4];
    #pragma unroll
    for (int i = 0; i < 4; ++i)
        #pragma unroll
        for (int j = 0; j < 4; ++j) {
            acc[i][j]  = 0.0f;
            dacc[i][j] = 0.0;
        }

    // prologue: stage K-tile 0 into registers
    float4 xa = *(const float4*)(xg);
    float4 xb = *(const float4*)(xg2);
    float4 wa = *(const float4*)(wg);
    float4 wb = *(const float4*)(wg2);

    for (int s = 0; s < KSTEPS; ++s) {
        // write staged registers to LDS (transposed: [k][row])
        {
            const float* pxa = (const float*)&xa;
            const float* pxb = (const float*)&xb;
            const float* pwa = (const float*)&wa;
            const float* pwb = (const float*)&wb;
            #pragma unroll
            for (int j = 0; j < 4; ++j) {
                xs[4 * c0 + j][r0]      = pxa[j];
                xs[4 * c0 + j][r0 + 32] = pxb[j];
                ws[4 * c0 + j][r0]      = pwa[j];
                ws[4 * c0 + j][r0 + 32] = pwb[j];
            }
        }
        __syncthreads();

        // issue next K-tile global loads early; latency hides under compute
        if (s + 1 < KSTEPS) {
            const int k0 = (s + 1) * BK;
            xa = *(const float4*)(xg + k0);
            xb = *(const float4*)(xg2 + k0);
            wa = *(const float4*)(wg + k0);
            wb = *(const float4*)(wg2 + k0);
        }

        #pragma unroll
        for (int kk = 0; kk < BK; ++kk) {
            float4 a = *(const float4*)&xs[kk][ty * 4];
            float4 b = *(const float4*)&ws[kk][tx * 4];
            const float* ap = (const float*)&a;
            const float* bp = (const float*)&b;
            #pragma unroll
            for (int i = 0; i < 4; ++i)
                #pragma unroll
                for (int j = 0; j < 4; ++j)
                    acc[i][j] = fmaf(ap[i], bp[j], acc[i][j]);
        }

        // fold fp32 chunk into fp64 master every 2 tiles (64 K-terms)
        if (s & 1) {
            #pragma unroll
            for (int i = 0; i < 4; ++i)
                #pragma unroll
                for (int j = 0; j < 4; ++j) {
                    dacc[i][j] += (double)acc[i][j];
                    acc[i][j] = 0.0f;
                }
        }
        __syncthreads();  // all reads done before next store
    }

    // Epilogue: per token, top-2 across the 16 lanes sharing ty (lanes are
    // contiguous within a wave; xor masks 1,2,4,8 stay inside the group).
    float* out_w = out;
    float* out_e = out + (size_t)2 * ntok;

    #pragma unroll
    for (int i = 0; i < 4; ++i) {
        float v1 = -3.0e38f, v2 = -3.0e38f;
        int   i1 = 0x7fffffff, i2 = 0x7fffffff;
        #pragma unroll
        for (int j = 0; j < 4; ++j) {
            float v = (float)dacc[i][j];
            int   id = tx * 4 + j;
            if (v > v1 || (v == v1 && id < i1)) {
                v2 = v1; i2 = i1; v1 = v; i1 = id;
            } else if (v > v2 || (v == v2 && id < i2)) {
                v2 = v; i2 = id;
            }
        }
        // butterfly top-2 merge over the 16-lane expert group
        #pragma unroll
        for (int m = 1; m < 16; m <<= 1) {
            float ov1 = __shfl_xor(v1, m, 64);
            int   oi1 = __shfl_xor(i1, m, 64);
            float ov2 = __shfl_xor(v2, m, 64);
            int   oi2 = __shfl_xor(i2, m, 64);
            bool ofirst = (ov1 > v1) || (ov1 == v1 && oi1 < i1);
            if (ofirst) {
                // other's best wins; second = better of (ov2) vs (our old v1)
                bool s2 = (ov2 > v1) || (ov2 == v1 && oi2 < i1);
                v2 = s2 ? ov2 : v1;  i2 = s2 ? oi2 : i1;
                v1 = ov1;            i1 = oi1;
            } else {
                bool s2 = (ov1 > v2) || (ov1 == v2 && oi1 < i2);
                v2 = s2 ? ov1 : v2;  i2 = s2 ? oi1 : i2;
            }
        }

        if (tx == 0) {
            int tok = tok0 + ty * 4 + i;
            float e  = expf(v2 - v1);         // <= 1
            float d  = 1.0f + e;
            float w1 = 1.0f / d;
            float w2 = e / d;
            out_w[2 * tok + 0] = w1;
            out_w[2 * tok + 1] = w2;
            out_e[2 * tok + 0] = (float)i1;
            out_e[2 * tok + 1] = (float)i2;
        }
    }
}

extern "C" void kernel_launch(void* const* d_in, const int* in_sizes, int n_in,
                              void* d_out, int out_size, void* d_ws, size_t ws_size,
                              hipStream_t stream) {
    const float* x = (const float*)d_in[0];
    const float* W = (const float*)d_in[1];
    float* out = (float*)d_out;
    const int ntok = in_sizes[0] / D_MODEL;  // 4*8192 = 32768

    dim3 grid(ntok / BM);
    dim3 block(NTHR);
    moe_router_kernel<<<grid, block, 0, stream>>>(x, W, out, ntok);
}